// Round 1
// baseline (2289.470 us; speedup 1.0000x reference)
//
#include <hip/hip_runtime.h>
#include <math.h>

constexpr int D = 512;        // embedding dim
constexpr int KCL = 128;      // clusters
constexpr float BETA_C = 5.0f;
constexpr int KC = 32;        // k-chunk for pass A
constexpr int GSPLIT = 128;   // split-K groups for pass B

// ---------------- row inverse L2 norms ----------------
__global__ __launch_bounds__(256) void norm_kernel(const float* __restrict__ x,
                                                   float* __restrict__ inv_norm, int n) {
    int wid  = (int)((blockIdx.x * blockDim.x + threadIdx.x) >> 6);
    int lane = threadIdx.x & 63;
    if (wid >= n) return;
    const float4* xr = reinterpret_cast<const float4*>(x) + (size_t)wid * (D / 4);
    float4 a = xr[lane];
    float4 b = xr[lane + 64];
    float s = a.x*a.x + a.y*a.y + a.z*a.z + a.w*a.w
            + b.x*b.x + b.y*b.y + b.z*b.z + b.w*b.w;
    #pragma unroll
    for (int m = 32; m; m >>= 1) s += __shfl_xor(s, m, 64);
    if (lane == 0) inv_norm[wid] = 1.0f / sqrtf(s);
}

// ---------------- pass A: r = softmax(beta * s_i * (x @ mu^T)) ----------------
// FIN=false: writes r' = r * s_i to r_out, accumulates cluster_r via atomics.
// FIN=true : writes plain r to r_out, no atomics.
template<bool FIN>
__global__ __launch_bounds__(256) void passA_kernel(
    const float* __restrict__ x, const float* __restrict__ mu,
    const float* __restrict__ inv_norm, float* __restrict__ r_out,
    float* __restrict__ cluster_r, int n)
{
    __shared__ float As[128 * 36];   // [row][k], stride 36 (16B aligned)
    __shared__ float Bs[KC * 132];   // [k][cluster], stride 132 (16B aligned)
    __shared__ float part[16 * 128]; // per-thread-row cluster partials

    const int t  = threadIdx.x;
    const int tr = t >> 4;   // 0..15 -> rows tr*8..tr*8+7
    const int tc = t & 15;   // cols tc*4..+3 and 64+tc*4..+3
    const int rowBase = blockIdx.x * 128;

    float acc[8][8];
    #pragma unroll
    for (int i = 0; i < 8; ++i)
        #pragma unroll
        for (int j = 0; j < 8; ++j) acc[i][j] = 0.f;

    for (int kb = 0; kb < D; kb += KC) {
        // stage A tile: 128 rows x 32 k
        #pragma unroll
        for (int u = 0; u < 4; ++u) {
            int f   = t + u * 256;        // 0..1023
            int row = f >> 3;
            int kc  = (f & 7) << 2;
            int gr  = rowBase + row;
            float4 v = make_float4(0.f, 0.f, 0.f, 0.f);
            if (gr < n) v = *reinterpret_cast<const float4*>(x + (size_t)gr * D + kb + kc);
            *reinterpret_cast<float4*>(&As[row * 36 + kc]) = v;
        }
        // stage B tile transposed: mu[128][kb..kb+31] -> Bs[k][cluster]
        #pragma unroll
        for (int u = 0; u < 4; ++u) {
            int f   = t + u * 256;
            int col = f >> 3;
            int kc  = (f & 7) << 2;
            float4 v = *reinterpret_cast<const float4*>(mu + (size_t)col * D + kb + kc);
            Bs[(kc + 0) * 132 + col] = v.x;
            Bs[(kc + 1) * 132 + col] = v.y;
            Bs[(kc + 2) * 132 + col] = v.z;
            Bs[(kc + 3) * 132 + col] = v.w;
        }
        __syncthreads();
        #pragma unroll
        for (int kg = 0; kg < KC; kg += 4) {
            float4 b0[4], b1[4];
            #pragma unroll
            for (int kk = 0; kk < 4; ++kk) {
                b0[kk] = *reinterpret_cast<const float4*>(&Bs[(kg + kk) * 132 + tc * 4]);
                b1[kk] = *reinterpret_cast<const float4*>(&Bs[(kg + kk) * 132 + 64 + tc * 4]);
            }
            #pragma unroll
            for (int i = 0; i < 8; ++i) {
                float4 a = *reinterpret_cast<const float4*>(&As[(tr * 8 + i) * 36 + kg]);
                float av[4] = {a.x, a.y, a.z, a.w};
                #pragma unroll
                for (int kk = 0; kk < 4; ++kk) {
                    acc[i][0] += av[kk] * b0[kk].x;
                    acc[i][1] += av[kk] * b0[kk].y;
                    acc[i][2] += av[kk] * b0[kk].z;
                    acc[i][3] += av[kk] * b0[kk].w;
                    acc[i][4] += av[kk] * b1[kk].x;
                    acc[i][5] += av[kk] * b1[kk].y;
                    acc[i][6] += av[kk] * b1[kk].z;
                    acc[i][7] += av[kk] * b1[kk].w;
                }
            }
        }
        __syncthreads();
    }

    // -------- softmax per row (16 lanes share a row-group) --------
    float sv[8];
    int   grr[8];
    bool  valid[8];
    #pragma unroll
    for (int i = 0; i < 8; ++i) {
        int gr = rowBase + tr * 8 + i;
        grr[i]  = gr;
        valid[i] = (gr < n);
        sv[i]   = valid[i] ? inv_norm[gr] : 0.f;
    }

    float csum[8];
    #pragma unroll
    for (int j = 0; j < 8; ++j) csum[j] = 0.f;

    #pragma unroll
    for (int i = 0; i < 8; ++i) {
        float bs = BETA_C * sv[i];
        float lg[8];
        float mx = -3.0e38f;
        #pragma unroll
        for (int j = 0; j < 8; ++j) { lg[j] = bs * acc[i][j]; mx = fmaxf(mx, lg[j]); }
        #pragma unroll
        for (int m = 1; m < 16; m <<= 1) mx = fmaxf(mx, __shfl_xor(mx, m, 64));
        float e[8];
        float sum = 0.f;
        #pragma unroll
        for (int j = 0; j < 8; ++j) { e[j] = __expf(lg[j] - mx); sum += e[j]; }
        #pragma unroll
        for (int m = 1; m < 16; m <<= 1) sum += __shfl_xor(sum, m, 64);
        float rinv = 1.0f / sum;
        if (valid[i]) {
            float r[8];
            #pragma unroll
            for (int j = 0; j < 8; ++j) r[j] = e[j] * rinv;
            if (!FIN) {
                #pragma unroll
                for (int j = 0; j < 8; ++j) csum[j] += r[j];
                float sc = sv[i];
                float4 o0 = make_float4(r[0] * sc, r[1] * sc, r[2] * sc, r[3] * sc);
                float4 o1 = make_float4(r[4] * sc, r[5] * sc, r[6] * sc, r[7] * sc);
                *reinterpret_cast<float4*>(r_out + (size_t)grr[i] * KCL + tc * 4)      = o0;
                *reinterpret_cast<float4*>(r_out + (size_t)grr[i] * KCL + 64 + tc * 4) = o1;
            } else {
                float4 o0 = make_float4(r[0], r[1], r[2], r[3]);
                float4 o1 = make_float4(r[4], r[5], r[6], r[7]);
                *reinterpret_cast<float4*>(r_out + (size_t)grr[i] * KCL + tc * 4)      = o0;
                *reinterpret_cast<float4*>(r_out + (size_t)grr[i] * KCL + 64 + tc * 4) = o1;
            }
        }
    }

    if (!FIN) {
        part[tr * 128 + tc * 4 + 0]      = csum[0];
        part[tr * 128 + tc * 4 + 1]      = csum[1];
        part[tr * 128 + tc * 4 + 2]      = csum[2];
        part[tr * 128 + tc * 4 + 3]      = csum[3];
        part[tr * 128 + 64 + tc * 4 + 0] = csum[4];
        part[tr * 128 + 64 + tc * 4 + 1] = csum[5];
        part[tr * 128 + 64 + tc * 4 + 2] = csum[6];
        part[tr * 128 + 64 + tc * 4 + 3] = csum[7];
        __syncthreads();
        if (t < 128) {
            float v = 0.f;
            #pragma unroll
            for (int g = 0; g < 16; ++g) v += part[g * 128 + t];
            atomicAdd(&cluster_r[t], v);
        }
    }
}

// ---------------- pass B: partials[g] = r'_chunk^T @ x_chunk ----------------
__global__ __launch_bounds__(256) void passB_kernel(
    const float* __restrict__ rp, const float* __restrict__ x,
    float* __restrict__ partials, int n, int chunk)
{
    __shared__ float Rs[32 * 132];  // [row][cluster]
    __shared__ float Xs[32 * 132];  // [row][dcol]

    const int t = threadIdx.x;
    const int a = t >> 4;           // cluster group: clusters a*8..+7
    const int b = t & 15;           // d cols: dbase + b*4..+3 and dbase+64+b*4..+3
    const int dbase = blockIdx.x * 128;
    const int r0 = blockIdx.y * chunk;
    const int r1 = min(n, r0 + chunk);

    float acc[8][8];
    #pragma unroll
    for (int i = 0; i < 8; ++i)
        #pragma unroll
        for (int j = 0; j < 8; ++j) acc[i][j] = 0.f;

    for (int ib = r0; ib < r1; ib += 32) {
        #pragma unroll
        for (int u = 0; u < 4; ++u) {
            int f  = t + u * 256;     // 0..1023
            int ii = f >> 5;
            int c4 = (f & 31) << 2;
            int gr = ib + ii;
            float4 rv = make_float4(0.f, 0.f, 0.f, 0.f);
            float4 xv = make_float4(0.f, 0.f, 0.f, 0.f);
            if (gr < r1) {
                rv = *reinterpret_cast<const float4*>(rp + (size_t)gr * KCL + c4);
                xv = *reinterpret_cast<const float4*>(x + (size_t)gr * D + dbase + c4);
            }
            *reinterpret_cast<float4*>(&Rs[ii * 132 + c4]) = rv;
            *reinterpret_cast<float4*>(&Xs[ii * 132 + c4]) = xv;
        }
        __syncthreads();
        #pragma unroll 4
        for (int ii = 0; ii < 32; ++ii) {
            float4 rv0 = *reinterpret_cast<const float4*>(&Rs[ii * 132 + a * 8]);
            float4 rv1 = *reinterpret_cast<const float4*>(&Rs[ii * 132 + a * 8 + 4]);
            float4 xv0 = *reinterpret_cast<const float4*>(&Xs[ii * 132 + b * 4]);
            float4 xv1 = *reinterpret_cast<const float4*>(&Xs[ii * 132 + 64 + b * 4]);
            float rr[8] = {rv0.x, rv0.y, rv0.z, rv0.w, rv1.x, rv1.y, rv1.z, rv1.w};
            #pragma unroll
            for (int i = 0; i < 8; ++i) {
                acc[i][0] += rr[i] * xv0.x;
                acc[i][1] += rr[i] * xv0.y;
                acc[i][2] += rr[i] * xv0.z;
                acc[i][3] += rr[i] * xv0.w;
                acc[i][4] += rr[i] * xv1.x;
                acc[i][5] += rr[i] * xv1.y;
                acc[i][6] += rr[i] * xv1.z;
                acc[i][7] += rr[i] * xv1.w;
            }
        }
        __syncthreads();
    }

    float* pb = partials + (size_t)blockIdx.y * (KCL * D);
    #pragma unroll
    for (int i = 0; i < 8; ++i) {
        int c = a * 8 + i;
        float4 o0 = make_float4(acc[i][0], acc[i][1], acc[i][2], acc[i][3]);
        float4 o1 = make_float4(acc[i][4], acc[i][5], acc[i][6], acc[i][7]);
        *reinterpret_cast<float4*>(pb + (size_t)c * D + dbase + b * 4)      = o0;
        *reinterpret_cast<float4*>(pb + (size_t)c * D + dbase + 64 + b * 4) = o1;
    }
}

// ---------------- reduce: mu = (sum_g partials[g]) / cluster_r ----------------
__global__ __launch_bounds__(256) void reduce_kernel(
    const float* __restrict__ partials, const float* __restrict__ cluster_r,
    float* __restrict__ mu_out)
{
    int idx = blockIdx.x * 256 + threadIdx.x;   // 0..65535
    float s = 0.f;
    #pragma unroll 8
    for (int g = 0; g < GSPLIT; ++g) s += partials[(size_t)g * (KCL * D) + idx];
    int c = idx >> 9;                            // / D
    mu_out[idx] = s / cluster_r[c];
}

extern "C" void kernel_launch(void* const* d_in, const int* in_sizes, int n_in,
                              void* d_out, int out_size, void* d_ws, size_t ws_size,
                              hipStream_t stream)
{
    const float* x   = (const float*)d_in[0];
    const float* mu0 = (const float*)d_in[1];
    const int n = in_sizes[0] / D;   // 100000

    char* ws = (char*)d_ws;
    size_t off = 0;
    auto alloc = [&](size_t bytes) { size_t cur = off; off += (bytes + 255) & ~(size_t)255; return cur; };
    float* inv_norm = (float*)(ws + alloc((size_t)n * 4));
    float* r_ws     = (float*)(ws + alloc((size_t)n * KCL * 4));
    float* parts    = (float*)(ws + alloc((size_t)GSPLIT * KCL * D * 4));
    float* cr       = (float*)(ws + alloc(512));

    float* mu_a = (float*)(ws + alloc((size_t)KCL * D * 4));
    float* mu_b = (float*)(ws + alloc((size_t)KCL * D * 4));

    float* mu_final = (float*)d_out;            // first 128*512 floats
    float* r_final  = (float*)d_out + KCL * D;  // then n*128 floats

    const int chunk   = (n + GSPLIT - 1) / GSPLIT;
    const int ablocks = (n + 127) / 128;

    // row norms
    norm_kernel<<<dim3((n + 3) / 4), 256, 0, stream>>>(x, inv_norm, n);

    const float* mu_cur = mu0;
    float* mu_tgt[3] = {mu_a, mu_b, mu_final};
    for (int it = 0; it < 3; ++it) {
        hipMemsetAsync(cr, 0, 512, stream);
        passA_kernel<false><<<dim3(ablocks), 256, 0, stream>>>(x, mu_cur, inv_norm, r_ws, cr, n);
        passB_kernel<<<dim3(4, GSPLIT), 256, 0, stream>>>(r_ws, x, parts, n, chunk);
        reduce_kernel<<<dim3((KCL * D) / 256), 256, 0, stream>>>(parts, cr, mu_tgt[it]);
        mu_cur = mu_tgt[it];
    }
    passA_kernel<true><<<dim3(ablocks), 256, 0, stream>>>(x, mu_cur, inv_norm, r_final, nullptr, n);
}

// Round 2
// 1231.114 us; speedup vs baseline: 1.8597x; 1.8597x over previous
//
#include <hip/hip_runtime.h>
#include <math.h>

constexpr int D = 512;        // embedding dim
constexpr int KCL = 128;      // clusters
constexpr float BETA_C = 5.0f;
constexpr int GSPLIT = 256;   // split-K groups for pass B

typedef __attribute__((ext_vector_type(8))) short short8;
typedef __attribute__((ext_vector_type(4))) float f32x4;

typedef const __attribute__((address_space(1))) unsigned int* gptr_t;
typedef __attribute__((address_space(3))) unsigned int* sptr_t;

static __device__ __forceinline__ unsigned short f2bf(float f) {
    unsigned u = __builtin_bit_cast(unsigned, f);
    unsigned r = (u + 0x7FFFu + ((u >> 16) & 1u)) >> 16;
    return (unsigned short)r;
}
static __device__ __forceinline__ float bf2f(unsigned short h) {
    unsigned u = ((unsigned)h) << 16;
    return __builtin_bit_cast(float, u);
}
static __device__ __forceinline__ void split_bf(float v, unsigned short& h, unsigned short& lo) {
    h = f2bf(v);
    lo = f2bf(v - bf2f(h));
}

// ---------------- conversion: x -> x_hi/x_lo bf16 + inv row norms ----------------
__global__ __launch_bounds__(256) void conv_x_kernel(const float* __restrict__ x,
        unsigned short* __restrict__ xh, unsigned short* __restrict__ xl,
        float* __restrict__ inv_norm, int n)
{
    int row  = blockIdx.x * 4 + (threadIdx.x >> 6);
    int lane = threadIdx.x & 63;
    if (row >= n) return;
    const float4* xr = reinterpret_cast<const float4*>(x + (size_t)row * D);
    float4 f0 = xr[lane];
    float4 f1 = xr[lane + 64];
    float s = f0.x*f0.x + f0.y*f0.y + f0.z*f0.z + f0.w*f0.w
            + f1.x*f1.x + f1.y*f1.y + f1.z*f1.z + f1.w*f1.w;
    #pragma unroll
    for (int m = 32; m; m >>= 1) s += __shfl_xor(s, m, 64);
    if (lane == 0) inv_norm[row] = 1.0f / sqrtf(s);

    ushort4 h0, l0, h1, l1;
    split_bf(f0.x, h0.x, l0.x); split_bf(f0.y, h0.y, l0.y);
    split_bf(f0.z, h0.z, l0.z); split_bf(f0.w, h0.w, l0.w);
    split_bf(f1.x, h1.x, l1.x); split_bf(f1.y, h1.y, l1.y);
    split_bf(f1.z, h1.z, l1.z); split_bf(f1.w, h1.w, l1.w);

    ushort4* xhr = reinterpret_cast<ushort4*>(xh + (size_t)row * D);
    ushort4* xlr = reinterpret_cast<ushort4*>(xl + (size_t)row * D);
    xhr[lane]      = h0;
    xhr[lane + 64] = h1;
    xlr[lane]      = l0;
    xlr[lane + 64] = l1;
}

// ---------------- conversion: mu fp32 -> hi/lo bf16 (for mu0) ----------------
__global__ __launch_bounds__(256) void conv_mu_kernel(const float* __restrict__ mu,
        unsigned short* __restrict__ mh, unsigned short* __restrict__ ml)
{
    int i = blockIdx.x * 256 + threadIdx.x;   // * 4 elements
    float4 v = reinterpret_cast<const float4*>(mu)[i];
    ushort4 h, l;
    split_bf(v.x, h.x, l.x); split_bf(v.y, h.y, l.y);
    split_bf(v.z, h.z, l.z); split_bf(v.w, h.w, l.w);
    reinterpret_cast<ushort4*>(mh)[i] = h;
    reinterpret_cast<ushort4*>(ml)[i] = l;
}

// ---------------- pass A (MFMA): r = softmax(beta * s_i * (x @ mu^T)) ----------------
// Tile: 128 rows x 128 clusters, KC=32. 4 waves, wave w owns rows w*32..w*32+31.
// A = x rows (row-major), B^T = mu rows (row-major) -> both frags contiguous ds_read_b128.
// Split product: hi*hi + hi*lo + lo*hi (fp32 MFMA accumulate).
template<bool FIN>
__global__ __launch_bounds__(256) void passA_mfma_kernel(
    const unsigned short* __restrict__ xh, const unsigned short* __restrict__ xl,
    const unsigned short* __restrict__ mh, const unsigned short* __restrict__ ml,
    const float* __restrict__ inv_norm, float* __restrict__ r_out,
    float* __restrict__ cluster_r, int n)
{
    __shared__ unsigned short lds[4][128 * 32];  // Ah, Al, Bh, Bl : [row][k] bf16
    __shared__ float part[4 * 128];

    const int t  = threadIdx.x;
    const int w  = t >> 6;
    const int l  = t & 63;
    const int fr = l & 15;          // fragment row/col
    const int fb = (l >> 4) * 8;    // k-offset (ushorts) within fragment row
    const int rowBase = blockIdx.x * 128;

    f32x4 acc[2][8];
    #pragma unroll
    for (int m = 0; m < 2; ++m)
        #pragma unroll
        for (int nn = 0; nn < 8; ++nn) acc[m][nn] = (f32x4){0.f, 0.f, 0.f, 0.f};

    // staging source pointers: chunk c = t + u*256 covers tile byte range c*16
    const unsigned short* pAh[2]; const unsigned short* pAl[2];
    const unsigned short* pBh[2]; const unsigned short* pBl[2];
    #pragma unroll
    for (int u = 0; u < 2; ++u) {
        int c = t + u * 256;
        int row = c >> 2;
        int kc  = (c & 3) * 8;
        int ga  = min(rowBase + row, n - 1);
        pAh[u] = xh + (size_t)ga * D + kc;
        pAl[u] = xl + (size_t)ga * D + kc;
        pBh[u] = mh + (size_t)row * D + kc;
        pBl[u] = ml + (size_t)row * D + kc;
    }

    for (int kb = 0; kb < D; kb += 32) {
        #pragma unroll
        for (int u = 0; u < 2; ++u) {
            int c = t + u * 256;
            __builtin_amdgcn_global_load_lds((gptr_t)pAh[u], (sptr_t)&lds[0][c * 8], 16, 0, 0);
            __builtin_amdgcn_global_load_lds((gptr_t)pAl[u], (sptr_t)&lds[1][c * 8], 16, 0, 0);
            __builtin_amdgcn_global_load_lds((gptr_t)pBh[u], (sptr_t)&lds[2][c * 8], 16, 0, 0);
            __builtin_amdgcn_global_load_lds((gptr_t)pBl[u], (sptr_t)&lds[3][c * 8], 16, 0, 0);
            pAh[u] += 32; pAl[u] += 32; pBh[u] += 32; pBl[u] += 32;
        }
        __syncthreads();

        short8 ah0 = *reinterpret_cast<const short8*>(&lds[0][(w * 32 +  0 + fr) * 32 + fb]);
        short8 ah1 = *reinterpret_cast<const short8*>(&lds[0][(w * 32 + 16 + fr) * 32 + fb]);
        short8 al0 = *reinterpret_cast<const short8*>(&lds[1][(w * 32 +  0 + fr) * 32 + fb]);
        short8 al1 = *reinterpret_cast<const short8*>(&lds[1][(w * 32 + 16 + fr) * 32 + fb]);
        #pragma unroll
        for (int nn = 0; nn < 8; ++nn) {
            short8 bh = *reinterpret_cast<const short8*>(&lds[2][(nn * 16 + fr) * 32 + fb]);
            short8 bl = *reinterpret_cast<const short8*>(&lds[3][(nn * 16 + fr) * 32 + fb]);
            acc[0][nn] = __builtin_amdgcn_mfma_f32_16x16x32_bf16(ah0, bh, acc[0][nn], 0, 0, 0);
            acc[1][nn] = __builtin_amdgcn_mfma_f32_16x16x32_bf16(ah1, bh, acc[1][nn], 0, 0, 0);
            acc[0][nn] = __builtin_amdgcn_mfma_f32_16x16x32_bf16(ah0, bl, acc[0][nn], 0, 0, 0);
            acc[1][nn] = __builtin_amdgcn_mfma_f32_16x16x32_bf16(ah1, bl, acc[1][nn], 0, 0, 0);
            acc[0][nn] = __builtin_amdgcn_mfma_f32_16x16x32_bf16(al0, bh, acc[0][nn], 0, 0, 0);
            acc[1][nn] = __builtin_amdgcn_mfma_f32_16x16x32_bf16(al1, bh, acc[1][nn], 0, 0, 0);
        }
        __syncthreads();
    }

    // -------- softmax: D[row][col], col = nn*16 + fr, row = base + (l>>4)*4 + rr --------
    float csum[8];
    #pragma unroll
    for (int nn = 0; nn < 8; ++nn) csum[nn] = 0.f;

    #pragma unroll
    for (int m = 0; m < 2; ++m) {
        #pragma unroll
        for (int rr = 0; rr < 4; ++rr) {
            int row = rowBase + w * 32 + m * 16 + (l >> 4) * 4 + rr;
            bool valid = row < n;
            float sv = inv_norm[min(row, n - 1)];
            float bs = BETA_C * sv;
            float lg[8];
            float mx = -3.0e38f;
            #pragma unroll
            for (int nn = 0; nn < 8; ++nn) { lg[nn] = bs * acc[m][nn][rr]; mx = fmaxf(mx, lg[nn]); }
            #pragma unroll
            for (int sh = 1; sh < 16; sh <<= 1) mx = fmaxf(mx, __shfl_xor(mx, sh, 64));
            float e[8];
            float sum = 0.f;
            #pragma unroll
            for (int nn = 0; nn < 8; ++nn) { e[nn] = __expf(lg[nn] - mx); sum += e[nn]; }
            #pragma unroll
            for (int sh = 1; sh < 16; sh <<= 1) sum += __shfl_xor(sum, sh, 64);
            float rinv = 1.0f / sum;
            if (valid) {
                float* ro = r_out + (size_t)row * KCL + fr;
                if (!FIN) {
                    #pragma unroll
                    for (int nn = 0; nn < 8; ++nn) {
                        float rv = e[nn] * rinv;
                        csum[nn] += rv;
                        ro[nn * 16] = rv * sv;   // r' = r * s_i (pre-scaled for pass B)
                    }
                } else {
                    #pragma unroll
                    for (int nn = 0; nn < 8; ++nn) ro[nn * 16] = e[nn] * rinv;
                }
            }
        }
    }

    if (!FIN) {
        #pragma unroll
        for (int nn = 0; nn < 8; ++nn) {
            csum[nn] += __shfl_xor(csum[nn], 16, 64);
            csum[nn] += __shfl_xor(csum[nn], 32, 64);
        }
        if (l < 16) {
            #pragma unroll
            for (int nn = 0; nn < 8; ++nn) part[w * 128 + nn * 16 + l] = csum[nn];
        }
        __syncthreads();
        if (t < 128) {
            atomicAdd(&cluster_r[t], part[t] + part[128 + t] + part[256 + t] + part[384 + t]);
        }
    }
}

// ---------------- pass B: partials[g] = r'_chunk^T @ x_chunk (fp32 VALU) ----------------
__global__ __launch_bounds__(256) void passB_kernel(
    const float* __restrict__ rp, const float* __restrict__ x,
    float* __restrict__ partials, int n, int chunk)
{
    __shared__ float Rs[32 * 132];  // [row][cluster]
    __shared__ float Xs[32 * 132];  // [row][dcol]

    const int t = threadIdx.x;
    const int a = t >> 4;           // cluster group: clusters a*8..+7
    const int b = t & 15;           // d cols: dbase + b*4..+3 and dbase+64+b*4..+3
    const int dbase = blockIdx.x * 128;
    const int r0 = blockIdx.y * chunk;
    const int r1 = min(n, r0 + chunk);

    float acc[8][8];
    #pragma unroll
    for (int i = 0; i < 8; ++i)
        #pragma unroll
        for (int j = 0; j < 8; ++j) acc[i][j] = 0.f;

    for (int ib = r0; ib < r1; ib += 32) {
        #pragma unroll
        for (int u = 0; u < 4; ++u) {
            int f  = t + u * 256;     // 0..1023
            int ii = f >> 5;
            int c4 = (f & 31) << 2;
            int gr = ib + ii;
            float4 rv = make_float4(0.f, 0.f, 0.f, 0.f);
            float4 xv = make_float4(0.f, 0.f, 0.f, 0.f);
            if (gr < r1) {
                rv = *reinterpret_cast<const float4*>(rp + (size_t)gr * KCL + c4);
                xv = *reinterpret_cast<const float4*>(x + (size_t)gr * D + dbase + c4);
            }
            *reinterpret_cast<float4*>(&Rs[ii * 132 + c4]) = rv;
            *reinterpret_cast<float4*>(&Xs[ii * 132 + c4]) = xv;
        }
        __syncthreads();
        #pragma unroll 4
        for (int ii = 0; ii < 32; ++ii) {
            float4 rv0 = *reinterpret_cast<const float4*>(&Rs[ii * 132 + a * 8]);
            float4 rv1 = *reinterpret_cast<const float4*>(&Rs[ii * 132 + a * 8 + 4]);
            float4 xv0 = *reinterpret_cast<const float4*>(&Xs[ii * 132 + b * 4]);
            float4 xv1 = *reinterpret_cast<const float4*>(&Xs[ii * 132 + 64 + b * 4]);
            float rr[8] = {rv0.x, rv0.y, rv0.z, rv0.w, rv1.x, rv1.y, rv1.z, rv1.w};
            #pragma unroll
            for (int i = 0; i < 8; ++i) {
                acc[i][0] += rr[i] * xv0.x;
                acc[i][1] += rr[i] * xv0.y;
                acc[i][2] += rr[i] * xv0.z;
                acc[i][3] += rr[i] * xv0.w;
                acc[i][4] += rr[i] * xv1.x;
                acc[i][5] += rr[i] * xv1.y;
                acc[i][6] += rr[i] * xv1.z;
                acc[i][7] += rr[i] * xv1.w;
            }
        }
        __syncthreads();
    }

    float* pb = partials + (size_t)blockIdx.y * (KCL * D);
    #pragma unroll
    for (int i = 0; i < 8; ++i) {
        int c = a * 8 + i;
        float4 o0 = make_float4(acc[i][0], acc[i][1], acc[i][2], acc[i][3]);
        float4 o1 = make_float4(acc[i][4], acc[i][5], acc[i][6], acc[i][7]);
        *reinterpret_cast<float4*>(pb + (size_t)c * D + dbase + b * 4)      = o0;
        *reinterpret_cast<float4*>(pb + (size_t)c * D + dbase + 64 + b * 4) = o1;
    }
}

// ---------------- reduce: mu = (sum_g partials[g]) / cluster_r ; emit hi/lo bf16 ----------------
__global__ __launch_bounds__(256) void reduce_kernel(
    const float* __restrict__ partials, const float* __restrict__ cluster_r,
    float* __restrict__ mu_out, unsigned short* __restrict__ mh, unsigned short* __restrict__ ml)
{
    int idx = blockIdx.x * 256 + threadIdx.x;   // 0..65535
    float s = 0.f;
    #pragma unroll 8
    for (int g = 0; g < GSPLIT; ++g) s += partials[(size_t)g * (KCL * D) + idx];
    int c = idx >> 9;                            // / D
    float m = s / cluster_r[c];
    mu_out[idx] = m;
    unsigned short h, lo;
    split_bf(m, h, lo);
    mh[idx] = h;
    ml[idx] = lo;
}

extern "C" void kernel_launch(void* const* d_in, const int* in_sizes, int n_in,
                              void* d_out, int out_size, void* d_ws, size_t ws_size,
                              hipStream_t stream)
{
    const float* x   = (const float*)d_in[0];
    const float* mu0 = (const float*)d_in[1];
    const int n = in_sizes[0] / D;   // 100000

    char* ws = (char*)d_ws;
    size_t off = 0;
    auto alloc = [&](size_t bytes) { size_t cur = off; off += (bytes + 255) & ~(size_t)255; return cur; };
    float*          inv_norm = (float*)(ws + alloc((size_t)n * 4));
    float*          r_ws     = (float*)(ws + alloc((size_t)n * KCL * 4));
    float*          parts    = (float*)(ws + alloc((size_t)GSPLIT * KCL * D * 4));
    float*          cr       = (float*)(ws + alloc(512));
    float*          mu_a     = (float*)(ws + alloc((size_t)KCL * D * 4));
    float*          mu_b     = (float*)(ws + alloc((size_t)KCL * D * 4));
    unsigned short* xh       = (unsigned short*)(ws + alloc((size_t)n * D * 2));
    unsigned short* xl       = (unsigned short*)(ws + alloc((size_t)n * D * 2));
    unsigned short* muh      = (unsigned short*)(ws + alloc((size_t)KCL * D * 2));
    unsigned short* mul      = (unsigned short*)(ws + alloc((size_t)KCL * D * 2));

    float* mu_final = (float*)d_out;            // first 128*512 floats
    float* r_final  = (float*)d_out + KCL * D;  // then n*128 floats

    const int chunk   = (n + GSPLIT - 1) / GSPLIT;
    const int ablocks = (n + 127) / 128;

    conv_x_kernel<<<dim3((n + 3) / 4), 256, 0, stream>>>(x, xh, xl, inv_norm, n);
    conv_mu_kernel<<<dim3((KCL * D) / 1024), 256, 0, stream>>>(mu0, muh, mul);

    float* mu_tgt[3] = {mu_a, mu_b, mu_final};
    for (int it = 0; it < 3; ++it) {
        hipMemsetAsync(cr, 0, 512, stream);
        passA_mfma_kernel<false><<<dim3(ablocks), 256, 0, stream>>>(xh, xl, muh, mul, inv_norm, r_ws, cr, n);
        passB_kernel<<<dim3(4, GSPLIT), 256, 0, stream>>>(r_ws, x, parts, n, chunk);
        reduce_kernel<<<dim3((KCL * D) / 256), 256, 0, stream>>>(parts, cr, mu_tgt[it], muh, mul);
    }
    passA_mfma_kernel<true><<<dim3(ablocks), 256, 0, stream>>>(xh, xl, muh, mul, inv_norm, r_final, nullptr, n);
}